// Round 15
// baseline (151.199 us; speedup 1.0000x reference)
//
#include <hip/hip_runtime.h>

typedef _Float16 half8 __attribute__((ext_vector_type(8)));
typedef float floatx4 __attribute__((ext_vector_type(4)));
typedef int intx4 __attribute__((ext_vector_type(4)));
typedef int intx8 __attribute__((ext_vector_type(8)));

#define SCALE_POS 2.0f
#define SCALE_NEG 40.0f
#define THRESH 0.5f
#define MARGIN 0.1f
#define EPSV 1e-5f

// order-preserving float<->uint map (no NaNs present)
__device__ __forceinline__ unsigned f2ord(float f) {
    unsigned u = __float_as_uint(f);
    return (u & 0x80000000u) ? ~u : (u | 0x80000000u);
}
__device__ __forceinline__ float ord2f(unsigned e) {
    unsigned v = (e & 0x80000000u) ? (e & 0x7fffffffu) : ~e;
    return __uint_as_float(v);
}

#define ORD_POS_INF 0xff800000u   // f2ord(+inf)
#define ORD_NEG_INF 0x007fffffu   // f2ord(-inf)

// ---- kernel 1: fp32 -> fp8 e4m3 (OCP, RNE via HW cvt) + stat/counter init ----
__global__ void k_init(const float* __restrict__ feats,
                       unsigned char* __restrict__ f8,
                       unsigned* __restrict__ minp, unsigned* __restrict__ maxn,
                       float* __restrict__ psum, float* __restrict__ nsum,
                       unsigned* __restrict__ cnts,
                       int total4, int B) {
    int i = blockIdx.x * blockDim.x + threadIdx.x;
    if (i < total4) {
        float4 v = ((const float4*)feats)[i];
        int w = 0;
        w = __builtin_amdgcn_cvt_pk_fp8_f32(v.x, v.y, w, false);  // bytes 0,1
        w = __builtin_amdgcn_cvt_pk_fp8_f32(v.z, v.w, w, true);   // bytes 2,3
        ((int*)f8)[i] = w;
    }
    if (i < B) {
        minp[i] = ORD_POS_INF;
        maxn[i] = ORD_NEG_INF;
        psum[i] = 0.f;
        nsum[i] = 0.f;
    }
    if (i < 2048) cnts[i] = 0;   // top @0; stripe s @ (1+s)*32
}

// =====================================================================
// kernel 2: MX-fp8 symmetric GEMM, DIRECT GLOBAL->VGPR (no LDS, no
// barriers). 1056 half-tile blocks x 128 thr (2 waves, each a full
// 64x64 worker: 16 mfma_scale_f32_16x16x128_f8f6f4 per K=128 iter).
// Each lane loads its fragments straight from the L2-resident 4MB fp8
// matrix (2 dwordx4 per fragment). Removes the 2-barrier K-loop's
// vmcnt(0) drain (the structural stall of all 50-57us bf16 variants):
// the compiler tracks per-load vmcnt(N), keeping next-iter loads in
// flight across MFMAs — the AITER-style pipelining the barrier
// structure can't express. Epilogue identical to R14.
// =====================================================================
__global__ void __launch_bounds__(128)
k_gemm_h(const unsigned char* __restrict__ f8,
         const int* __restrict__ labels,
         unsigned* __restrict__ minp_ord,
         unsigned* __restrict__ maxn_ord,
         _Float16* __restrict__ simh,
         int D, int nb) {      // D = 1024 elements = 1024 bytes/row
    const int bid = blockIdx.x;
    int t = bid >> 1;
    const int h = bid & 1;
    int rb = 0, rem = t;
    while (rem >= nb - rb) { rem -= nb - rb; ++rb; }
    const int cb = rb + rem;
    const int rowBase = rb * 128;
    const int colBase = cb * 128 + h * 64;

    const int tid = threadIdx.x;        // 0..127
    const int lane = tid & 63;
    const int wave = tid >> 6;          // 0..1 : row half (64 rows each)
    const int q = lane >> 4;
    const int cIn = lane & 15;

    // per-lane fragment row pointers (A: this wave's 64 rows; B: 64 cols)
    const unsigned char* aRow[4];
    const unsigned char* bRow[4];
#pragma unroll
    for (int i = 0; i < 4; ++i) {
        aRow[i] = f8 + (size_t)(rowBase + wave * 64 + i * 16 + cIn) * D;
        bRow[i] = f8 + (size_t)(colBase + i * 16 + cIn) * D;
    }

    floatx4 acc[4][4] = {};

    const int KT = D >> 7;               // 8 iters of K=128
    for (int kt = 0; kt < KT; ++kt) {
        const int e0 = kt * 8 + q * 2;   // intx4 index of this lane's 32B k-slice
        intx8 a[4], b[4];
#pragma unroll
        for (int i = 0; i < 4; ++i) {
            intx4 lo = ((const intx4*)aRow[i])[e0];
            intx4 hi = ((const intx4*)aRow[i])[e0 + 1];
            a[i] = __builtin_shufflevector(lo, hi, 0, 1, 2, 3, 4, 5, 6, 7);
        }
#pragma unroll
        for (int i = 0; i < 4; ++i) {
            intx4 lo = ((const intx4*)bRow[i])[e0];
            intx4 hi = ((const intx4*)bRow[i])[e0 + 1];
            b[i] = __builtin_shufflevector(lo, hi, 0, 1, 2, 3, 4, 5, 6, 7);
        }
#pragma unroll
        for (int i = 0; i < 4; ++i)
#pragma unroll
            for (int j = 0; j < 4; ++j)
                acc[i][j] = __builtin_amdgcn_mfma_scale_f32_16x16x128_f8f6f4(
                    a[i], b[j], acc[i][j], 0, 0,       // cbsz=fp8, blgp=fp8
                    0, 0x7f7f7f7f,                     // opsel_a, scale_a (unity E8M0)
                    0, 0x7f7f7f7f);                    // opsel_b, scale_b
    }

    // labels straight from global (L2/L1-hot, no LDS needed)
    int rLabv[16];
#pragma unroll
    for (int mi = 0; mi < 4; ++mi)
#pragma unroll
        for (int rr = 0; rr < 4; ++rr)
            rLabv[mi * 4 + rr] = labels[rowBase + wave * 64 + mi * 16 + q * 4 + rr];
    int cLabv[4];
#pragma unroll
    for (int ni = 0; ni < 4; ++ni)
        cLabv[ni] = labels[colBase + ni * 16 + cIn];

    // ---- fp16 store: thread-major, 64 contiguous halves (R13 layout) ----
    {
        half8* dst = (half8*)(simh + (size_t)bid * 8192 + (size_t)tid * 64);
#pragma unroll
        for (int mi = 0; mi < 4; ++mi) {
            half8 h0, h1;
#pragma unroll
            for (int ni = 0; ni < 2; ++ni)
#pragma unroll
                for (int rr = 0; rr < 4; ++rr) {
                    h0[ni * 4 + rr] = (_Float16)acc[mi][ni][rr];
                    h1[ni * 4 + rr] = (_Float16)acc[mi][ni + 2][rr];
                }
            dst[mi * 2] = h0;
            dst[mi * 2 + 1] = h1;
        }
    }

    // ---- row stats ----
#pragma unroll
    for (int mi = 0; mi < 4; ++mi)
#pragma unroll
        for (int rr = 0; rr < 4; ++rr) {
            const int rLoc = wave * 64 + mi * 16 + q * 4 + rr;
            const int rLab = rLabv[mi * 4 + rr];
            float vmin = 1e30f, vmax = -1e30f;
#pragma unroll
            for (int ni = 0; ni < 4; ++ni) {
                float s = acc[mi][ni][rr];
                if (rLab == cLabv[ni]) {
                    if (s < 1.0f - EPSV) vmin = fminf(vmin, s);
                } else {
                    vmax = fmaxf(vmax, s);
                }
            }
#pragma unroll
            for (int off = 8; off; off >>= 1) {
                vmin = fminf(vmin, __shfl_xor(vmin, off, 16));
                vmax = fmaxf(vmax, __shfl_xor(vmax, off, 16));
            }
            if (cIn == 0) {
                if (vmin < 1e30f) atomicMin(&minp_ord[rowBase + rLoc], f2ord(vmin));
                if (vmax > -1e30f) atomicMax(&maxn_ord[rowBase + rLoc], f2ord(vmax));
            }
        }

    // ---- col stats via symmetry (off-diagonal tiles only) ----
    if (rb != cb) {
#pragma unroll
        for (int ni = 0; ni < 4; ++ni) {
            const int cLab = cLabv[ni];
            float vmin = 1e30f, vmax = -1e30f;
#pragma unroll
            for (int mi = 0; mi < 4; ++mi)
#pragma unroll
                for (int rr = 0; rr < 4; ++rr) {
                    float s = acc[mi][ni][rr];
                    if (rLabv[mi * 4 + rr] == cLab) {
                        if (s < 1.0f - EPSV) vmin = fminf(vmin, s);
                    } else {
                        vmax = fmaxf(vmax, s);
                    }
                }
            vmin = fminf(vmin, __shfl_xor(vmin, 16, 64));
            vmin = fminf(vmin, __shfl_xor(vmin, 32, 64));
            vmax = fmaxf(vmax, __shfl_xor(vmax, 16, 64));
            vmax = fmaxf(vmax, __shfl_xor(vmax, 32, 64));
            if (q == 0) {
                const int cLoc = ni * 16 + cIn;
                if (vmin < 1e30f) atomicMin(&minp_ord[colBase + cLoc], f2ord(vmin));
                if (vmax > -1e30f) atomicMax(&maxn_ord[colBase + cLoc], f2ord(vmax));
            }
        }
    }
}

// =====================================================================
// kernel 3 (unchanged from R13/R14): pass 2, 528 blocks x 256 threads +
// fused final reduction behind the hierarchical RELAXED done-counter.
// =====================================================================
__global__ void __launch_bounds__(256)
k_sum2f(const _Float16* __restrict__ simh,
        const int* __restrict__ labels,
        const unsigned* __restrict__ minp_ord,
        const unsigned* __restrict__ maxn_ord,
        float* __restrict__ psum, float* __restrict__ nsum,
        unsigned* __restrict__ cnts,   // top @0; stripe s @ (1+s)*32
        float* __restrict__ out,
        int nb, int B, int NT) {
    __shared__ int labR[128], labC[128];
    __shared__ float mpR[128], mnR[128], mpC[128], mnC[128];
    __shared__ float red[4];
    __shared__ unsigned lastflag;

    int t = blockIdx.x;
    int rb = 0, rem = t;
    while (rem >= nb - rb) { rem -= nb - rb; ++rb; }
    const int cb = rb + rem;
    const int rowBase = rb * 128;

    const int tid = threadIdx.x;
    const int sub = tid >> 7;
    const int stid = tid & 127;
    const int wave = stid >> 6;
    const int lane = tid & 63;
    const int q = lane >> 4;
    const int cIn = lane & 15;
    const int colBase = cb * 128 + sub * 64;

    if (tid < 128) {
        labR[tid] = labels[rowBase + tid];
        mpR[tid] = ord2f(minp_ord[rowBase + tid]) - MARGIN;   // neg kept if s > this
        mnR[tid] = ord2f(maxn_ord[rowBase + tid]) + MARGIN;   // pos kept if s < this
    } else {
        const int j = tid - 128;
        labC[j] = labels[cb * 128 + j];
        mpC[j] = ord2f(minp_ord[cb * 128 + j]) - MARGIN;
        mnC[j] = ord2f(maxn_ord[cb * 128 + j]) + MARGIN;
    }
    __syncthreads();

    int cLabv[4];
    float mpCv[4], mnCv[4];
#pragma unroll
    for (int ni = 0; ni < 4; ++ni) {
        const int j = sub * 64 + ni * 16 + cIn;
        cLabv[ni] = labC[j];
        mpCv[ni] = mpC[j];
        mnCv[ni] = mnC[j];
    }

    const half8* src = (const half8*)(simh + (size_t)(2 * t + sub) * 8192 + (size_t)stid * 64);
    half8 hv[8];
#pragma unroll
    for (int v = 0; v < 8; ++v) hv[v] = src[v];

    float cps[4] = {}, cns[4] = {};
    const bool offd = (rb != cb);

#pragma unroll
    for (int mi = 0; mi < 4; ++mi)
#pragma unroll
        for (int rr = 0; rr < 4; ++rr) {
            const int rLoc = wave * 64 + mi * 16 + q * 4 + rr;
            const int rLab = labR[rLoc];
            const float gateN = mpR[rLoc];
            const float gateP = mnR[rLoc];
            float rp = 0.f, rn = 0.f;
#pragma unroll
            for (int ni = 0; ni < 4; ++ni) {
                const int idx = mi * 16 + ni * 4 + rr;
                const float s = (float)hv[idx >> 3][idx & 7];
                if (rLab == cLabv[ni]) {
                    if (s < 1.0f - EPSV) {
                        float ev = __expf(-SCALE_POS * (s - THRESH));
                        if (s < gateP) rp += ev;
                        if (offd && s < mnCv[ni]) cps[ni] += ev;
                    }
                } else {
                    float ev = __expf(SCALE_NEG * (s - THRESH));
                    if (s > gateN) rn += ev;
                    if (offd && s > mpCv[ni]) cns[ni] += ev;
                }
            }
#pragma unroll
            for (int off = 8; off; off >>= 1) {
                rp += __shfl_xor(rp, off, 16);
                rn += __shfl_xor(rn, off, 16);
            }
            if (cIn == 0) {
                if (rp != 0.f) atomicAdd(&psum[rowBase + rLoc], rp);
                if (rn != 0.f) atomicAdd(&nsum[rowBase + rLoc], rn);
            }
        }
    if (offd) {
#pragma unroll
        for (int ni = 0; ni < 4; ++ni) {
            cps[ni] += __shfl_xor(cps[ni], 16, 64);
            cps[ni] += __shfl_xor(cps[ni], 32, 64);
            cns[ni] += __shfl_xor(cns[ni], 16, 64);
            cns[ni] += __shfl_xor(cns[ni], 32, 64);
            if (q == 0) {
                const int cLoc = ni * 16 + cIn;
                if (cps[ni] != 0.f) atomicAdd(&psum[colBase + cLoc], cps[ni]);
                if (cns[ni] != 0.f) atomicAdd(&nsum[colBase + cLoc], cns[ni]);
            }
        }
    }

    // ---- hierarchical done-counter (all RELAXED — no fences) ----
    __syncthreads();
    if (tid == 0) {
        const unsigned stripe = (unsigned)blockIdx.x & 31u;
        const unsigned stripe_target = (unsigned)((NT - (int)stripe + 31) / 32);
        unsigned prev = __hip_atomic_fetch_add(&cnts[(1 + stripe) * 32], 1u,
                                               __ATOMIC_RELAXED, __HIP_MEMORY_SCOPE_AGENT);
        unsigned lf = 0u;
        if (prev == stripe_target - 1u) {
            unsigned ptop = __hip_atomic_fetch_add(&cnts[0], 1u,
                                                   __ATOMIC_RELAXED, __HIP_MEMORY_SCOPE_AGENT);
            lf = (ptop == 31u) ? 1u : 0u;
        }
        lastflag = lf;
    }
    __syncthreads();
    if (lastflag) {
        float a = 0.f;
        for (int i = tid; i < B; i += 256) {
            float pv = atomicAdd(&psum[i], 0.0f);   // coherent returning atomic
            float nv = atomicAdd(&nsum[i], 0.0f);
            if (pv > 0.f && nv > 0.f)
                a += log1pf(pv) * (1.0f / SCALE_POS) + log1pf(nv) * (1.0f / SCALE_NEG);
        }
#pragma unroll
        for (int off = 32; off; off >>= 1) a += __shfl_down(a, off, 64);
        if ((tid & 63) == 0) red[tid >> 6] = a;
        __syncthreads();
        if (tid == 0) out[0] = (red[0] + red[1] + red[2] + red[3]) / (float)B;
    }
}

extern "C" void kernel_launch(void* const* d_in, const int* in_sizes, int n_in,
                              void* d_out, int out_size, void* d_ws, size_t ws_size,
                              hipStream_t stream) {
    const float* feats = (const float*)d_in[0];
    const int* labels = (const int*)d_in[1];
    const int B = in_sizes[1];            // 4096
    const int D = in_sizes[0] / B;        // 1024
    const int nb = B / 128;               // 32
    const int NT = nb * (nb + 1) / 2;     // 528
    const int NH = NT * 2;                // 1056 half-tiles
    const int total4 = B * D / 4;

    char* ws = (char*)d_ws;
    unsigned char* f8 = (unsigned char*)ws;
    size_t off = (size_t)B * D;           // 4 MB fp8
    unsigned* minp = (unsigned*)(ws + off); off += (size_t)B * 4;
    unsigned* maxn = (unsigned*)(ws + off); off += (size_t)B * 4;
    float* psum = (float*)(ws + off); off += (size_t)B * 4;
    float* nsum = (float*)(ws + off); off += (size_t)B * 4;
    unsigned* cnts = (unsigned*)(ws + off); off += 8192;  // 2048 u32, zeroed by k_init
    _Float16* simh = (_Float16*)(ws + ((off + 255) & ~(size_t)255));
    float* outp = (float*)d_out;

    k_init<<<(total4 + 255) / 256, 256, 0, stream>>>(feats, f8, minp, maxn,
                                                     psum, nsum, cnts, total4, B);

    // 1056 blocks x 128 thr — direct-from-L2 MX-fp8 GEMM (no LDS/barriers)
    k_gemm_h<<<NH, 128, 0, stream>>>(f8, labels, minp, maxn, simh, D, nb);

    // 528 blocks x 256 thr, hierarchical relaxed done-counter
    k_sum2f<<<NT, 256, 0, stream>>>(simh, labels, minp, maxn, psum, nsum,
                                    cnts, outp, nb, B, NT);
}

// Round 16
// 138.622 us; speedup vs baseline: 1.0907x; 1.0907x over previous
//
#include <hip/hip_runtime.h>

typedef _Float16 half8 __attribute__((ext_vector_type(8)));
typedef float floatx4 __attribute__((ext_vector_type(4)));
typedef int intx4 __attribute__((ext_vector_type(4)));
typedef int intx8 __attribute__((ext_vector_type(8)));
typedef __attribute__((address_space(1))) const void gvoid;
typedef __attribute__((address_space(3))) void svoid;

#define SCALE_POS 2.0f
#define SCALE_NEG 40.0f
#define THRESH 0.5f
#define MARGIN 0.1f
#define EPSV 1e-5f

// order-preserving float<->uint map (no NaNs present)
__device__ __forceinline__ unsigned f2ord(float f) {
    unsigned u = __float_as_uint(f);
    return (u & 0x80000000u) ? ~u : (u | 0x80000000u);
}
__device__ __forceinline__ float ord2f(unsigned e) {
    unsigned v = (e & 0x80000000u) ? (e & 0x7fffffffu) : ~e;
    return __uint_as_float(v);
}

#define ORD_POS_INF 0xff800000u   // f2ord(+inf)
#define ORD_NEG_INF 0x007fffffu   // f2ord(-inf)

// ---- kernel 1: fp32 -> fp8 e4m3 (OCP, RNE via HW cvt) + stat/counter init ----
__global__ void k_init(const float* __restrict__ feats,
                       unsigned char* __restrict__ f8,
                       unsigned* __restrict__ minp, unsigned* __restrict__ maxn,
                       float* __restrict__ psum, float* __restrict__ nsum,
                       unsigned* __restrict__ cnts,
                       int total4, int B) {
    int i = blockIdx.x * blockDim.x + threadIdx.x;
    if (i < total4) {
        float4 v = ((const float4*)feats)[i];
        int w = 0;
        w = __builtin_amdgcn_cvt_pk_fp8_f32(v.x, v.y, w, false);  // bytes 0,1
        w = __builtin_amdgcn_cvt_pk_fp8_f32(v.z, v.w, w, true);   // bytes 2,3
        ((int*)f8)[i] = w;
    }
    if (i < B) {
        minp[i] = ORD_POS_INF;
        maxn[i] = ORD_NEG_INF;
        psum[i] = 0.f;
        nsum[i] = 0.f;
    }
    if (i < 2048) cnts[i] = 0;   // top @0; stripe s @ (1+s)*32
}

// =====================================================================
// kernel 2: MX-fp8 symmetric GEMM over 128x64 HALF-tiles (R14 geometry)
// + DOUBLE-BUFFERED LDS PREFETCH. 1056 blocks x 128 thr (2 waves, each
// a full 64x64 worker, 16 mfma_scale_f32_16x16x128_f8f6f4 per K=128
// iter). Stage k+1's global_load_lds are issued BEFORE stage k's
// compute, so the barrier's vmcnt(0) drain waits on loads that had a
// full compute phase in flight (R14's drain ate ~300-400 cyc of cold L2
// latency x8 iters at ~2 resident blocks/CU — nothing hid it).
// XOR-block swizzle on the global source side (LDS side stays
// base+lane*16 per m104); epilogue identical to R14.
// =====================================================================
__global__ void __launch_bounds__(128, 2)
k_gemm_h(const unsigned char* __restrict__ f8,
         const int* __restrict__ labels,
         unsigned* __restrict__ minp_ord,
         unsigned* __restrict__ maxn_ord,
         _Float16* __restrict__ simh,
         int D, int nb) {      // D = 1024 elements = 1024 bytes/row
    __shared__ __align__(16) unsigned char As[2][128 * 128];  // 2 x 16 KB
    __shared__ __align__(16) unsigned char Bs[2][64 * 128];   // 2 x 8 KB
    __shared__ int labR[128], labC[64];

    const int bid = blockIdx.x;
    int t = bid >> 1;
    const int h = bid & 1;
    int rb = 0, rem = t;
    while (rem >= nb - rb) { rem -= nb - rb; ++rb; }
    const int cb = rb + rem;
    const int rowBase = rb * 128;
    const int colBase = cb * 128 + h * 64;

    const int tid = threadIdx.x;        // 0..127
    const int lane = tid & 63;
    const int wave = tid >> 6;          // 0..1 : row half (64 rows each)
    const int q = lane >> 4;
    const int cIn = lane & 15;

    labR[tid] = labels[rowBase + tid];
    if (tid < 64) labC[tid] = labels[colBase + tid];

    // staging: 24 chunks of 1KB (8 rows x 128B). Wave handles 12.
    // lane i: subrow = i>>3, physical block = i&7, logical = (i&7)^(i>>3)
    const int subrow = lane >> 3;
    const int swz = (lane & 7) ^ subrow;     // logical 16B-block index
    const unsigned char* gP[12];
    int lOff[12];                             // offset within As/Bs buffer
    bool isA[12];
#pragma unroll
    for (int j = 0; j < 12; ++j) {
        const int c = wave * 12 + j;
        const int grow = (c < 16) ? (rowBase + c * 8 + subrow)
                                  : (colBase + (c - 16) * 8 + subrow);
        gP[j] = f8 + (size_t)grow * D + swz * 16;
        isA[j] = (c < 16);
        lOff[j] = ((c < 16) ? c * 1024 : (c - 16) * 1024) + lane * 16;
    }

    // fragment LDS offsets: row r, 32B k-group q = logical blocks 2q,2q+1
    int aOff0[4], aOff1[4], bOff0[4], bOff1[4];
#pragma unroll
    for (int i = 0; i < 4; ++i) {
        const int rA = wave * 64 + i * 16 + cIn;
        aOff0[i] = rA * 128 + ((2 * q) ^ (rA & 7)) * 16;
        aOff1[i] = rA * 128 + ((2 * q + 1) ^ (rA & 7)) * 16;
        const int rB = i * 16 + cIn;
        bOff0[i] = rB * 128 + ((2 * q) ^ (rB & 7)) * 16;
        bOff1[i] = rB * 128 + ((2 * q + 1) ^ (rB & 7)) * 16;
    }

    floatx4 acc[4][4] = {};

    const int KT = D >> 7;               // 8 iters of K=128

    // prefetch stage 0 into buffer 0
#pragma unroll
    for (int j = 0; j < 12; ++j)
        __builtin_amdgcn_global_load_lds((gvoid*)gP[j],
            (svoid*)((isA[j] ? As[0] : Bs[0]) + lOff[j]), 16, 0, 0);

    for (int kt = 0; kt < KT; ++kt) {
        const int cur = kt & 1;
        // barrier: drains vmcnt(0) -> buffer `cur` loads (issued one full
        // compute-phase ago) are complete; also protects `next` buffer
        // (its last readers finished the stage before last).
        __syncthreads();

        if (kt + 1 < KT) {
            const int nxt = cur ^ 1;
            const int kOff = (kt + 1) * 128;
#pragma unroll
            for (int j = 0; j < 12; ++j)
                __builtin_amdgcn_global_load_lds((gvoid*)(gP[j] + kOff),
                    (svoid*)((isA[j] ? As[nxt] : Bs[nxt]) + lOff[j]), 16, 0, 0);
        }

        const unsigned char* Ab = As[cur];
        const unsigned char* Bb = Bs[cur];
        intx8 a[4], b[4];
#pragma unroll
        for (int i = 0; i < 4; ++i) {
            intx4 lo = *(const intx4*)(Ab + aOff0[i]);
            intx4 hi = *(const intx4*)(Ab + aOff1[i]);
            a[i] = __builtin_shufflevector(lo, hi, 0, 1, 2, 3, 4, 5, 6, 7);
        }
#pragma unroll
        for (int i = 0; i < 4; ++i) {
            intx4 lo = *(const intx4*)(Bb + bOff0[i]);
            intx4 hi = *(const intx4*)(Bb + bOff1[i]);
            b[i] = __builtin_shufflevector(lo, hi, 0, 1, 2, 3, 4, 5, 6, 7);
        }
#pragma unroll
        for (int i = 0; i < 4; ++i)
#pragma unroll
            for (int j = 0; j < 4; ++j)
                acc[i][j] = __builtin_amdgcn_mfma_scale_f32_16x16x128_f8f6f4(
                    a[i], b[j], acc[i][j], 0, 0,       // cbsz=fp8, blgp=fp8
                    0, 0x7f7f7f7f,                     // opsel_a, scale_a (unity E8M0)
                    0, 0x7f7f7f7f);                    // opsel_b, scale_b
    }

    int rLabv[16];
#pragma unroll
    for (int mi = 0; mi < 4; ++mi)
#pragma unroll
        for (int rr = 0; rr < 4; ++rr)
            rLabv[mi * 4 + rr] = labR[wave * 64 + mi * 16 + q * 4 + rr];
    int cLabv[4];
#pragma unroll
    for (int ni = 0; ni < 4; ++ni)
        cLabv[ni] = labC[ni * 16 + cIn];

    // ---- fp16 store: thread-major, 64 contiguous halves (R13 layout) ----
    {
        half8* dst = (half8*)(simh + (size_t)bid * 8192 + (size_t)tid * 64);
#pragma unroll
        for (int mi = 0; mi < 4; ++mi) {
            half8 h0, h1;
#pragma unroll
            for (int ni = 0; ni < 2; ++ni)
#pragma unroll
                for (int rr = 0; rr < 4; ++rr) {
                    h0[ni * 4 + rr] = (_Float16)acc[mi][ni][rr];
                    h1[ni * 4 + rr] = (_Float16)acc[mi][ni + 2][rr];
                }
            dst[mi * 2] = h0;
            dst[mi * 2 + 1] = h1;
        }
    }

    // ---- row stats ----
#pragma unroll
    for (int mi = 0; mi < 4; ++mi)
#pragma unroll
        for (int rr = 0; rr < 4; ++rr) {
            const int rLoc = wave * 64 + mi * 16 + q * 4 + rr;
            const int rLab = rLabv[mi * 4 + rr];
            float vmin = 1e30f, vmax = -1e30f;
#pragma unroll
            for (int ni = 0; ni < 4; ++ni) {
                float s = acc[mi][ni][rr];
                if (rLab == cLabv[ni]) {
                    if (s < 1.0f - EPSV) vmin = fminf(vmin, s);
                } else {
                    vmax = fmaxf(vmax, s);
                }
            }
#pragma unroll
            for (int off = 8; off; off >>= 1) {
                vmin = fminf(vmin, __shfl_xor(vmin, off, 16));
                vmax = fmaxf(vmax, __shfl_xor(vmax, off, 16));
            }
            if (cIn == 0) {
                if (vmin < 1e30f) atomicMin(&minp_ord[rowBase + rLoc], f2ord(vmin));
                if (vmax > -1e30f) atomicMax(&maxn_ord[rowBase + rLoc], f2ord(vmax));
            }
        }

    // ---- col stats via symmetry (off-diagonal tiles only) ----
    if (rb != cb) {
#pragma unroll
        for (int ni = 0; ni < 4; ++ni) {
            const int cLab = cLabv[ni];
            float vmin = 1e30f, vmax = -1e30f;
#pragma unroll
            for (int mi = 0; mi < 4; ++mi)
#pragma unroll
                for (int rr = 0; rr < 4; ++rr) {
                    float s = acc[mi][ni][rr];
                    if (rLabv[mi * 4 + rr] == cLab) {
                        if (s < 1.0f - EPSV) vmin = fminf(vmin, s);
                    } else {
                        vmax = fmaxf(vmax, s);
                    }
                }
            vmin = fminf(vmin, __shfl_xor(vmin, 16, 64));
            vmin = fminf(vmin, __shfl_xor(vmin, 32, 64));
            vmax = fmaxf(vmax, __shfl_xor(vmax, 16, 64));
            vmax = fmaxf(vmax, __shfl_xor(vmax, 32, 64));
            if (q == 0) {
                const int cLoc = ni * 16 + cIn;
                if (vmin < 1e30f) atomicMin(&minp_ord[colBase + cLoc], f2ord(vmin));
                if (vmax > -1e30f) atomicMax(&maxn_ord[colBase + cLoc], f2ord(vmax));
            }
        }
    }
}

// =====================================================================
// kernel 3 (unchanged from R13/R14): pass 2, 528 blocks x 256 threads +
// fused final reduction behind the hierarchical RELAXED done-counter.
// =====================================================================
__global__ void __launch_bounds__(256)
k_sum2f(const _Float16* __restrict__ simh,
        const int* __restrict__ labels,
        const unsigned* __restrict__ minp_ord,
        const unsigned* __restrict__ maxn_ord,
        float* __restrict__ psum, float* __restrict__ nsum,
        unsigned* __restrict__ cnts,   // top @0; stripe s @ (1+s)*32
        float* __restrict__ out,
        int nb, int B, int NT) {
    __shared__ int labR[128], labC[128];
    __shared__ float mpR[128], mnR[128], mpC[128], mnC[128];
    __shared__ float red[4];
    __shared__ unsigned lastflag;

    int t = blockIdx.x;
    int rb = 0, rem = t;
    while (rem >= nb - rb) { rem -= nb - rb; ++rb; }
    const int cb = rb + rem;
    const int rowBase = rb * 128;

    const int tid = threadIdx.x;
    const int sub = tid >> 7;
    const int stid = tid & 127;
    const int wave = stid >> 6;
    const int lane = tid & 63;
    const int q = lane >> 4;
    const int cIn = lane & 15;
    const int colBase = cb * 128 + sub * 64;

    if (tid < 128) {
        labR[tid] = labels[rowBase + tid];
        mpR[tid] = ord2f(minp_ord[rowBase + tid]) - MARGIN;   // neg kept if s > this
        mnR[tid] = ord2f(maxn_ord[rowBase + tid]) + MARGIN;   // pos kept if s < this
    } else {
        const int j = tid - 128;
        labC[j] = labels[cb * 128 + j];
        mpC[j] = ord2f(minp_ord[cb * 128 + j]) - MARGIN;
        mnC[j] = ord2f(maxn_ord[cb * 128 + j]) + MARGIN;
    }
    __syncthreads();

    int cLabv[4];
    float mpCv[4], mnCv[4];
#pragma unroll
    for (int ni = 0; ni < 4; ++ni) {
        const int j = sub * 64 + ni * 16 + cIn;
        cLabv[ni] = labC[j];
        mpCv[ni] = mpC[j];
        mnCv[ni] = mnC[j];
    }

    const half8* src = (const half8*)(simh + (size_t)(2 * t + sub) * 8192 + (size_t)stid * 64);
    half8 hv[8];
#pragma unroll
    for (int v = 0; v < 8; ++v) hv[v] = src[v];

    float cps[4] = {}, cns[4] = {};
    const bool offd = (rb != cb);

#pragma unroll
    for (int mi = 0; mi < 4; ++mi)
#pragma unroll
        for (int rr = 0; rr < 4; ++rr) {
            const int rLoc = wave * 64 + mi * 16 + q * 4 + rr;
            const int rLab = labR[rLoc];
            const float gateN = mpR[rLoc];
            const float gateP = mnR[rLoc];
            float rp = 0.f, rn = 0.f;
#pragma unroll
            for (int ni = 0; ni < 4; ++ni) {
                const int idx = mi * 16 + ni * 4 + rr;
                const float s = (float)hv[idx >> 3][idx & 7];
                if (rLab == cLabv[ni]) {
                    if (s < 1.0f - EPSV) {
                        float ev = __expf(-SCALE_POS * (s - THRESH));
                        if (s < gateP) rp += ev;
                        if (offd && s < mnCv[ni]) cps[ni] += ev;
                    }
                } else {
                    float ev = __expf(SCALE_NEG * (s - THRESH));
                    if (s > gateN) rn += ev;
                    if (offd && s > mpCv[ni]) cns[ni] += ev;
                }
            }
#pragma unroll
            for (int off = 8; off; off >>= 1) {
                rp += __shfl_xor(rp, off, 16);
                rn += __shfl_xor(rn, off, 16);
            }
            if (cIn == 0) {
                if (rp != 0.f) atomicAdd(&psum[rowBase + rLoc], rp);
                if (rn != 0.f) atomicAdd(&nsum[rowBase + rLoc], rn);
            }
        }
    if (offd) {
#pragma unroll
        for (int ni = 0; ni < 4; ++ni) {
            cps[ni] += __shfl_xor(cps[ni], 16, 64);
            cps[ni] += __shfl_xor(cps[ni], 32, 64);
            cns[ni] += __shfl_xor(cns[ni], 16, 64);
            cns[ni] += __shfl_xor(cns[ni], 32, 64);
            if (q == 0) {
                const int cLoc = ni * 16 + cIn;
                if (cps[ni] != 0.f) atomicAdd(&psum[colBase + cLoc], cps[ni]);
                if (cns[ni] != 0.f) atomicAdd(&nsum[colBase + cLoc], cns[ni]);
            }
        }
    }

    // ---- hierarchical done-counter (all RELAXED — no fences) ----
    __syncthreads();
    if (tid == 0) {
        const unsigned stripe = (unsigned)blockIdx.x & 31u;
        const unsigned stripe_target = (unsigned)((NT - (int)stripe + 31) / 32);
        unsigned prev = __hip_atomic_fetch_add(&cnts[(1 + stripe) * 32], 1u,
                                               __ATOMIC_RELAXED, __HIP_MEMORY_SCOPE_AGENT);
        unsigned lf = 0u;
        if (prev == stripe_target - 1u) {
            unsigned ptop = __hip_atomic_fetch_add(&cnts[0], 1u,
                                                   __ATOMIC_RELAXED, __HIP_MEMORY_SCOPE_AGENT);
            lf = (ptop == 31u) ? 1u : 0u;
        }
        lastflag = lf;
    }
    __syncthreads();
    if (lastflag) {
        float a = 0.f;
        for (int i = tid; i < B; i += 256) {
            float pv = atomicAdd(&psum[i], 0.0f);   // coherent returning atomic
            float nv = atomicAdd(&nsum[i], 0.0f);
            if (pv > 0.f && nv > 0.f)
                a += log1pf(pv) * (1.0f / SCALE_POS) + log1pf(nv) * (1.0f / SCALE_NEG);
        }
#pragma unroll
        for (int off = 32; off; off >>= 1) a += __shfl_down(a, off, 64);
        if ((tid & 63) == 0) red[tid >> 6] = a;
        __syncthreads();
        if (tid == 0) out[0] = (red[0] + red[1] + red[2] + red[3]) / (float)B;
    }
}

extern "C" void kernel_launch(void* const* d_in, const int* in_sizes, int n_in,
                              void* d_out, int out_size, void* d_ws, size_t ws_size,
                              hipStream_t stream) {
    const float* feats = (const float*)d_in[0];
    const int* labels = (const int*)d_in[1];
    const int B = in_sizes[1];            // 4096
    const int D = in_sizes[0] / B;        // 1024
    const int nb = B / 128;               // 32
    const int NT = nb * (nb + 1) / 2;     // 528
    const int NH = NT * 2;                // 1056 half-tiles
    const int total4 = B * D / 4;

    char* ws = (char*)d_ws;
    unsigned char* f8 = (unsigned char*)ws;
    size_t off = (size_t)B * D;           // 4 MB fp8
    unsigned* minp = (unsigned*)(ws + off); off += (size_t)B * 4;
    unsigned* maxn = (unsigned*)(ws + off); off += (size_t)B * 4;
    float* psum = (float*)(ws + off); off += (size_t)B * 4;
    float* nsum = (float*)(ws + off); off += (size_t)B * 4;
    unsigned* cnts = (unsigned*)(ws + off); off += 8192;  // 2048 u32, zeroed by k_init
    _Float16* simh = (_Float16*)(ws + ((off + 255) & ~(size_t)255));
    float* outp = (float*)d_out;

    k_init<<<(total4 + 255) / 256, 256, 0, stream>>>(feats, f8, minp, maxn,
                                                     psum, nsum, cnts, total4, B);

    // 1056 blocks x 128 thr — MX-fp8 GEMM with double-buffered prefetch
    k_gemm_h<<<NH, 128, 0, stream>>>(f8, labels, minp, maxn, simh, D, nb);

    // 528 blocks x 256 thr, hierarchical relaxed done-counter
    k_sum2f<<<NT, 256, 0, stream>>>(simh, labels, minp, maxn, psum, nsum,
                                    cnts, outp, nb, B, NT);
}

// Round 17
// 136.827 us; speedup vs baseline: 1.1050x; 1.0131x over previous
//
#include <hip/hip_runtime.h>

typedef _Float16 half8 __attribute__((ext_vector_type(8)));
typedef float floatx4 __attribute__((ext_vector_type(4)));
typedef int intx4 __attribute__((ext_vector_type(4)));
typedef int intx8 __attribute__((ext_vector_type(8)));
typedef __attribute__((address_space(1))) const void gvoid;
typedef __attribute__((address_space(3))) void svoid;

#define SCALE_POS 2.0f
#define SCALE_NEG 40.0f
#define THRESH 0.5f
#define MARGIN 0.1f
#define EPSV 1e-5f

// order-preserving float<->uint map (no NaNs present)
__device__ __forceinline__ unsigned f2ord(float f) {
    unsigned u = __float_as_uint(f);
    return (u & 0x80000000u) ? ~u : (u | 0x80000000u);
}
__device__ __forceinline__ float ord2f(unsigned e) {
    unsigned v = (e & 0x80000000u) ? (e & 0x7fffffffu) : ~e;
    return __uint_as_float(v);
}

#define ORD_POS_INF 0xff800000u   // f2ord(+inf)
#define ORD_NEG_INF 0x007fffffu   // f2ord(-inf)

// ---- kernel 1: fp32 -> fp8 e4m3 (OCP, RNE via HW cvt) + stat/counter init ----
__global__ void k_init(const float* __restrict__ feats,
                       unsigned char* __restrict__ f8,
                       unsigned* __restrict__ minp, unsigned* __restrict__ maxn,
                       float* __restrict__ psum, float* __restrict__ nsum,
                       unsigned* __restrict__ cnts,
                       int total4, int B) {
    int i = blockIdx.x * blockDim.x + threadIdx.x;
    if (i < total4) {
        float4 v = ((const float4*)feats)[i];
        int w = 0;
        w = __builtin_amdgcn_cvt_pk_fp8_f32(v.x, v.y, w, false);  // bytes 0,1
        w = __builtin_amdgcn_cvt_pk_fp8_f32(v.z, v.w, w, true);   // bytes 2,3
        ((int*)f8)[i] = w;
    }
    if (i < B) {
        minp[i] = ORD_POS_INF;
        maxn[i] = ORD_NEG_INF;
        psum[i] = 0.f;
        nsum[i] = 0.f;
    }
    if (i < 2048) cnts[i] = 0;   // top @0; stripe s @ (1+s)*32
}

// =====================================================================
// kernel 2 (R14, the measured best): MX-fp8 symmetric GEMM over 128x64
// HALF-tiles. 1056 blocks x 128 thr (2 waves, each a full 64x64 worker,
// 16 mfma_scale_f32_16x16x128_f8f6f4 per K=128 iter, unity E8M0 scales).
// Single-buffered 2-barrier K-loop: measured equal-or-better than
// explicit dbuf (R16) and direct-global (R15) — the structural plateau
// of this K-loop shape at source level (guide m99-m141).
// XOR-block swizzle on the global source side (LDS side stays
// base+lane*16 per m104). Epilogue: row+col stats + fp16 tile store.
// =====================================================================
__global__ void __launch_bounds__(128, 2)
k_gemm_h(const unsigned char* __restrict__ f8,
         const int* __restrict__ labels,
         unsigned* __restrict__ minp_ord,
         unsigned* __restrict__ maxn_ord,
         _Float16* __restrict__ simh,
         int D, int nb) {      // D = 1024 elements = 1024 bytes/row
    __shared__ __align__(16) unsigned char As[128 * 128];  // 16 KB
    __shared__ __align__(16) unsigned char Bs[64 * 128];   // 8 KB
    __shared__ int labR[128], labC[64];

    const int bid = blockIdx.x;
    int t = bid >> 1;
    const int h = bid & 1;
    int rb = 0, rem = t;
    while (rem >= nb - rb) { rem -= nb - rb; ++rb; }
    const int cb = rb + rem;
    const int rowBase = rb * 128;
    const int colBase = cb * 128 + h * 64;

    const int tid = threadIdx.x;        // 0..127
    const int lane = tid & 63;
    const int wave = tid >> 6;          // 0..1 : row half (64 rows each)
    const int q = lane >> 4;
    const int cIn = lane & 15;

    labR[tid] = labels[rowBase + tid];
    if (tid < 64) labC[tid] = labels[colBase + tid];

    // staging: 24 chunks of 1KB (8 rows x 128B). Wave handles 12.
    // lane i: subrow = i>>3, physical block = i&7, logical = (i&7)^(i>>3)
    const int subrow = lane >> 3;
    const int swz = (lane & 7) ^ subrow;     // logical 16B-block index
    const unsigned char* gP[12];
    unsigned char* lP[12];
#pragma unroll
    for (int j = 0; j < 12; ++j) {
        const int c = wave * 12 + j;
        const int grow = (c < 16) ? (rowBase + c * 8 + subrow)
                                  : (colBase + (c - 16) * 8 + subrow);
        gP[j] = f8 + (size_t)grow * D + swz * 16;
        lP[j] = ((c < 16) ? (As + c * 1024) : (Bs + (c - 16) * 1024)) + lane * 16;
    }

    // fragment LDS offsets: row r, 32B k-group q = logical blocks 2q,2q+1
    // physical p = blk ^ (r&7)
    int aOff0[4], aOff1[4], bOff0[4], bOff1[4];
#pragma unroll
    for (int i = 0; i < 4; ++i) {
        const int rA = wave * 64 + i * 16 + cIn;
        aOff0[i] = rA * 128 + ((2 * q) ^ (rA & 7)) * 16;
        aOff1[i] = rA * 128 + ((2 * q + 1) ^ (rA & 7)) * 16;
        const int rB = i * 16 + cIn;
        bOff0[i] = rB * 128 + ((2 * q) ^ (rB & 7)) * 16;
        bOff1[i] = rB * 128 + ((2 * q + 1) ^ (rB & 7)) * 16;
    }

    floatx4 acc[4][4] = {};

    const int KT = D >> 7;               // 8 iters of K=128
    for (int kt = 0; kt < KT; ++kt) {
        const int kOff = kt * 128;
        __syncthreads();
#pragma unroll
        for (int j = 0; j < 12; ++j)
            __builtin_amdgcn_global_load_lds((gvoid*)(gP[j] + kOff), (svoid*)lP[j], 16, 0, 0);
        __syncthreads();

        intx8 a[4], b[4];
#pragma unroll
        for (int i = 0; i < 4; ++i) {
            intx4 lo = *(const intx4*)(As + aOff0[i]);
            intx4 hi = *(const intx4*)(As + aOff1[i]);
            a[i] = __builtin_shufflevector(lo, hi, 0, 1, 2, 3, 4, 5, 6, 7);
        }
#pragma unroll
        for (int i = 0; i < 4; ++i) {
            intx4 lo = *(const intx4*)(Bs + bOff0[i]);
            intx4 hi = *(const intx4*)(Bs + bOff1[i]);
            b[i] = __builtin_shufflevector(lo, hi, 0, 1, 2, 3, 4, 5, 6, 7);
        }
#pragma unroll
        for (int i = 0; i < 4; ++i)
#pragma unroll
            for (int j = 0; j < 4; ++j)
                acc[i][j] = __builtin_amdgcn_mfma_scale_f32_16x16x128_f8f6f4(
                    a[i], b[j], acc[i][j], 0, 0,       // cbsz=fp8, blgp=fp8
                    0, 0x7f7f7f7f,                     // opsel_a, scale_a (unity E8M0)
                    0, 0x7f7f7f7f);                    // opsel_b, scale_b
    }

    int rLabv[16];
#pragma unroll
    for (int mi = 0; mi < 4; ++mi)
#pragma unroll
        for (int rr = 0; rr < 4; ++rr)
            rLabv[mi * 4 + rr] = labR[wave * 64 + mi * 16 + q * 4 + rr];
    int cLabv[4];
#pragma unroll
    for (int ni = 0; ni < 4; ++ni)
        cLabv[ni] = labC[ni * 16 + cIn];

    // ---- fp16 store: thread-major, 64 contiguous halves (R13 layout) ----
    {
        half8* dst = (half8*)(simh + (size_t)bid * 8192 + (size_t)tid * 64);
#pragma unroll
        for (int mi = 0; mi < 4; ++mi) {
            half8 h0, h1;
#pragma unroll
            for (int ni = 0; ni < 2; ++ni)
#pragma unroll
                for (int rr = 0; rr < 4; ++rr) {
                    h0[ni * 4 + rr] = (_Float16)acc[mi][ni][rr];
                    h1[ni * 4 + rr] = (_Float16)acc[mi][ni + 2][rr];
                }
            dst[mi * 2] = h0;
            dst[mi * 2 + 1] = h1;
        }
    }

    // ---- row stats ----
#pragma unroll
    for (int mi = 0; mi < 4; ++mi)
#pragma unroll
        for (int rr = 0; rr < 4; ++rr) {
            const int rLoc = wave * 64 + mi * 16 + q * 4 + rr;
            const int rLab = rLabv[mi * 4 + rr];
            float vmin = 1e30f, vmax = -1e30f;
#pragma unroll
            for (int ni = 0; ni < 4; ++ni) {
                float s = acc[mi][ni][rr];
                if (rLab == cLabv[ni]) {
                    if (s < 1.0f - EPSV) vmin = fminf(vmin, s);
                } else {
                    vmax = fmaxf(vmax, s);
                }
            }
#pragma unroll
            for (int off = 8; off; off >>= 1) {
                vmin = fminf(vmin, __shfl_xor(vmin, off, 16));
                vmax = fmaxf(vmax, __shfl_xor(vmax, off, 16));
            }
            if (cIn == 0) {
                if (vmin < 1e30f) atomicMin(&minp_ord[rowBase + rLoc], f2ord(vmin));
                if (vmax > -1e30f) atomicMax(&maxn_ord[rowBase + rLoc], f2ord(vmax));
            }
        }

    // ---- col stats via symmetry (off-diagonal tiles only) ----
    if (rb != cb) {
#pragma unroll
        for (int ni = 0; ni < 4; ++ni) {
            const int cLab = cLabv[ni];
            float vmin = 1e30f, vmax = -1e30f;
#pragma unroll
            for (int mi = 0; mi < 4; ++mi)
#pragma unroll
                for (int rr = 0; rr < 4; ++rr) {
                    float s = acc[mi][ni][rr];
                    if (rLabv[mi * 4 + rr] == cLab) {
                        if (s < 1.0f - EPSV) vmin = fminf(vmin, s);
                    } else {
                        vmax = fmaxf(vmax, s);
                    }
                }
            vmin = fminf(vmin, __shfl_xor(vmin, 16, 64));
            vmin = fminf(vmin, __shfl_xor(vmin, 32, 64));
            vmax = fmaxf(vmax, __shfl_xor(vmax, 16, 64));
            vmax = fmaxf(vmax, __shfl_xor(vmax, 32, 64));
            if (q == 0) {
                const int cLoc = ni * 16 + cIn;
                if (vmin < 1e30f) atomicMin(&minp_ord[colBase + cLoc], f2ord(vmin));
                if (vmax > -1e30f) atomicMax(&maxn_ord[colBase + cLoc], f2ord(vmax));
            }
        }
    }
}

// =====================================================================
// kernel 3 (unchanged R13/R14): pass 2, 528 blocks x 256 threads +
// fused final reduction behind the hierarchical RELAXED done-counter.
// =====================================================================
__global__ void __launch_bounds__(256)
k_sum2f(const _Float16* __restrict__ simh,
        const int* __restrict__ labels,
        const unsigned* __restrict__ minp_ord,
        const unsigned* __restrict__ maxn_ord,
        float* __restrict__ psum, float* __restrict__ nsum,
        unsigned* __restrict__ cnts,   // top @0; stripe s @ (1+s)*32
        float* __restrict__ out,
        int nb, int B, int NT) {
    __shared__ int labR[128], labC[128];
    __shared__ float mpR[128], mnR[128], mpC[128], mnC[128];
    __shared__ float red[4];
    __shared__ unsigned lastflag;

    int t = blockIdx.x;
    int rb = 0, rem = t;
    while (rem >= nb - rb) { rem -= nb - rb; ++rb; }
    const int cb = rb + rem;
    const int rowBase = rb * 128;

    const int tid = threadIdx.x;
    const int sub = tid >> 7;
    const int stid = tid & 127;
    const int wave = stid >> 6;
    const int lane = tid & 63;
    const int q = lane >> 4;
    const int cIn = lane & 15;
    const int colBase = cb * 128 + sub * 64;

    if (tid < 128) {
        labR[tid] = labels[rowBase + tid];
        mpR[tid] = ord2f(minp_ord[rowBase + tid]) - MARGIN;   // neg kept if s > this
        mnR[tid] = ord2f(maxn_ord[rowBase + tid]) + MARGIN;   // pos kept if s < this
    } else {
        const int j = tid - 128;
        labC[j] = labels[cb * 128 + j];
        mpC[j] = ord2f(minp_ord[cb * 128 + j]) - MARGIN;
        mnC[j] = ord2f(maxn_ord[cb * 128 + j]) + MARGIN;
    }
    __syncthreads();

    int cLabv[4];
    float mpCv[4], mnCv[4];
#pragma unroll
    for (int ni = 0; ni < 4; ++ni) {
        const int j = sub * 64 + ni * 16 + cIn;
        cLabv[ni] = labC[j];
        mpCv[ni] = mpC[j];
        mnCv[ni] = mnC[j];
    }

    const half8* src = (const half8*)(simh + (size_t)(2 * t + sub) * 8192 + (size_t)stid * 64);
    half8 hv[8];
#pragma unroll
    for (int v = 0; v < 8; ++v) hv[v] = src[v];

    float cps[4] = {}, cns[4] = {};
    const bool offd = (rb != cb);

#pragma unroll
    for (int mi = 0; mi < 4; ++mi)
#pragma unroll
        for (int rr = 0; rr < 4; ++rr) {
            const int rLoc = wave * 64 + mi * 16 + q * 4 + rr;
            const int rLab = labR[rLoc];
            const float gateN = mpR[rLoc];
            const float gateP = mnR[rLoc];
            float rp = 0.f, rn = 0.f;
#pragma unroll
            for (int ni = 0; ni < 4; ++ni) {
                const int idx = mi * 16 + ni * 4 + rr;
                const float s = (float)hv[idx >> 3][idx & 7];
                if (rLab == cLabv[ni]) {
                    if (s < 1.0f - EPSV) {
                        float ev = __expf(-SCALE_POS * (s - THRESH));
                        if (s < gateP) rp += ev;
                        if (offd && s < mnCv[ni]) cps[ni] += ev;
                    }
                } else {
                    float ev = __expf(SCALE_NEG * (s - THRESH));
                    if (s > gateN) rn += ev;
                    if (offd && s > mpCv[ni]) cns[ni] += ev;
                }
            }
#pragma unroll
            for (int off = 8; off; off >>= 1) {
                rp += __shfl_xor(rp, off, 16);
                rn += __shfl_xor(rn, off, 16);
            }
            if (cIn == 0) {
                if (rp != 0.f) atomicAdd(&psum[rowBase + rLoc], rp);
                if (rn != 0.f) atomicAdd(&nsum[rowBase + rLoc], rn);
            }
        }
    if (offd) {
#pragma unroll
        for (int ni = 0; ni < 4; ++ni) {
            cps[ni] += __shfl_xor(cps[ni], 16, 64);
            cps[ni] += __shfl_xor(cps[ni], 32, 64);
            cns[ni] += __shfl_xor(cns[ni], 16, 64);
            cns[ni] += __shfl_xor(cns[ni], 32, 64);
            if (q == 0) {
                const int cLoc = ni * 16 + cIn;
                if (cps[ni] != 0.f) atomicAdd(&psum[colBase + cLoc], cps[ni]);
                if (cns[ni] != 0.f) atomicAdd(&nsum[colBase + cLoc], cns[ni]);
            }
        }
    }

    // ---- hierarchical done-counter (all RELAXED — no fences) ----
    __syncthreads();
    if (tid == 0) {
        const unsigned stripe = (unsigned)blockIdx.x & 31u;
        const unsigned stripe_target = (unsigned)((NT - (int)stripe + 31) / 32);
        unsigned prev = __hip_atomic_fetch_add(&cnts[(1 + stripe) * 32], 1u,
                                               __ATOMIC_RELAXED, __HIP_MEMORY_SCOPE_AGENT);
        unsigned lf = 0u;
        if (prev == stripe_target - 1u) {
            unsigned ptop = __hip_atomic_fetch_add(&cnts[0], 1u,
                                                   __ATOMIC_RELAXED, __HIP_MEMORY_SCOPE_AGENT);
            lf = (ptop == 31u) ? 1u : 0u;
        }
        lastflag = lf;
    }
    __syncthreads();
    if (lastflag) {
        float a = 0.f;
        for (int i = tid; i < B; i += 256) {
            float pv = atomicAdd(&psum[i], 0.0f);   // coherent returning atomic
            float nv = atomicAdd(&nsum[i], 0.0f);
            if (pv > 0.f && nv > 0.f)
                a += log1pf(pv) * (1.0f / SCALE_POS) + log1pf(nv) * (1.0f / SCALE_NEG);
        }
#pragma unroll
        for (int off = 32; off; off >>= 1) a += __shfl_down(a, off, 64);
        if ((tid & 63) == 0) red[tid >> 6] = a;
        __syncthreads();
        if (tid == 0) out[0] = (red[0] + red[1] + red[2] + red[3]) / (float)B;
    }
}

extern "C" void kernel_launch(void* const* d_in, const int* in_sizes, int n_in,
                              void* d_out, int out_size, void* d_ws, size_t ws_size,
                              hipStream_t stream) {
    const float* feats = (const float*)d_in[0];
    const int* labels = (const int*)d_in[1];
    const int B = in_sizes[1];            // 4096
    const int D = in_sizes[0] / B;        // 1024
    const int nb = B / 128;               // 32
    const int NT = nb * (nb + 1) / 2;     // 528
    const int NH = NT * 2;                // 1056 half-tiles
    const int total4 = B * D / 4;

    char* ws = (char*)d_ws;
    unsigned char* f8 = (unsigned char*)ws;
    size_t off = (size_t)B * D;           // 4 MB fp8
    unsigned* minp = (unsigned*)(ws + off); off += (size_t)B * 4;
    unsigned* maxn = (unsigned*)(ws + off); off += (size_t)B * 4;
    float* psum = (float*)(ws + off); off += (size_t)B * 4;
    float* nsum = (float*)(ws + off); off += (size_t)B * 4;
    unsigned* cnts = (unsigned*)(ws + off); off += 8192;  // 2048 u32, zeroed by k_init
    _Float16* simh = (_Float16*)(ws + ((off + 255) & ~(size_t)255));
    float* outp = (float*)d_out;

    k_init<<<(total4 + 255) / 256, 256, 0, stream>>>(feats, f8, minp, maxn,
                                                     psum, nsum, cnts, total4, B);

    // 1056 blocks x 128 thr — MX-fp8 K=128 GEMM (R14, measured best)
    k_gemm_h<<<NH, 128, 0, stream>>>(f8, labels, minp, maxn, simh, D, nb);

    // 528 blocks x 256 thr, hierarchical relaxed done-counter
    k_sum2f<<<NT, 256, 0, stream>>>(simh, labels, minp, maxn, psum, nsum,
                                    cnts, outp, nb, B, NT);
}